// Round 2
// baseline (2368.139 us; speedup 1.0000x reference)
//
#include <hip/hip_runtime.h>
#include <math.h>

// ---- problem constants ----
constexpr int NF        = 101;
constexpr int UNITS     = 125;
constexpr int THREE_U   = 375;
constexpr int OUT_DIM   = 202;
constexpr int B_TOT     = 4096;
constexpr int T_IN      = 70;
constexpr int TW        = 56;    // T - LAG warmup steps
constexpr int GAMMA_    = 28;
constexpr int KS_       = UNITS * OUT_DIM;     // 25250
constexpr int N_W       = KS_ + OUT_DIM;       // 25452
constexpr float CLOG    = 0.54132485466f;      // log(expm1(1))

// ws layout (floats)
constexpr int WBLK_OFF  = 0;                    // [26][375][4]  = 39000
constexpr int UBLK_OFF  = 39000;                // [32][375][4]  = 48000
constexpr int KBLK_OFF  = 87000;                // [28][32][202][4] = 723968
constexpr int BIAS_OFF  = 810968;               // [28][202] = 5656

constexpr int WKB = 26;   // ceil(101/4) -> padded to 104
constexpr int UKB = 32;   // ceil(125/4) -> padded to 128
constexpr int NTHR = 768; // 750-unit gemvs single-pass (98% eff); 12 waves/CU
constexpr int EB   = 16;  // batch rows per workgroup

__device__ __forceinline__ float softplusf_(float x) {
  return (x > 0.f) ? (x + log1pf(expf(-x))) : log1pf(expf(x));
}

// ---------- setup: transpose+pad W_k and U into k-blocked [kb][j][4] ----------
__global__ void setup_wu(const float* __restrict__ Wk, const float* __restrict__ U,
                         float* __restrict__ ws) {
  int idx = blockIdx.x * 256 + threadIdx.x;
  if (idx >= 87000) return;
  if (idx < 39000) {
    int c  = idx & 3;
    int j  = (idx >> 2) % THREE_U;
    int kb = idx / (THREE_U * 4);
    int k  = kb * 4 + c;
    ws[WBLK_OFF + idx] = (k < NF) ? Wk[k * THREE_U + j] : 0.f;
  } else {
    int i  = idx - 39000;
    int c  = i & 3;
    int j  = (i >> 2) % THREE_U;
    int kb = i / (THREE_U * 4);
    int k  = kb * 4 + c;
    ws[UBLK_OFF + i] = (k < UNITS) ? U[k * THREE_U + j] : 0.f;
  }
}

// ---------- setup: 28 variational dense kernels, k-blocked, + biases ----------
__global__ void setup_kb(const float* __restrict__ dv_loc, const float* __restrict__ dv_rho,
                         const float* __restrict__ eps_w0, const float* __restrict__ eps_w,
                         float* __restrict__ ws) {
  int idx = blockIdx.x * 256 + threadIdx.x;
  const int KTOT = 28 * 32 * OUT_DIM * 4;   // 723968
  if (idx >= KTOT + 28 * OUT_DIM) return;
  if (idx < KTOT) {
    int c  = idx & 3;
    int q  = idx >> 2;              // (s*32+kb)*202 + o
    int o  = q % OUT_DIM;
    int kb = (q / OUT_DIM) % 32;
    int s  = q / (OUT_DIM * 32);
    int k  = kb * 4 + c;
    float v = 0.f;
    if (k < UNITS) {
      int n = k * OUT_DIM + o;
      const float* er = (s == 0) ? eps_w0 : (eps_w + (size_t)(s - 1) * N_W);
      float sig = 1e-5f + 0.01f * softplusf_(CLOG + dv_rho[n]);
      v = dv_loc[n] + sig * er[n];
    }
    ws[KBLK_OFF + idx] = v;
  } else {
    int i = idx - KTOT;
    int o = i % OUT_DIM;
    int s = i / OUT_DIM;
    int n = KS_ + o;
    const float* er = (s == 0) ? eps_w0 : (eps_w + (size_t)(s - 1) * N_W);
    float sig = 1e-5f + 0.01f * softplusf_(CLOG + dv_rho[n]);
    ws[BIAS_OFF + i] = dv_loc[n] + sig * er[n];
  }
}

// ---------- per-WG GEMV tile: out[e][j] = bias[j] + sum_k in[e][k] * M[k][j] ----------
// M stored k-blocked: Mblk[(kb*J + j)*4 + c] = M[kb*4+c][j]
template<int J, int KB, int LDIN, int LDOUT>
__device__ __forceinline__ void gemv_tile(const float (*in)[LDIN], float (*outl)[LDOUT],
                                          const float* __restrict__ Mblk,
                                          const float* __restrict__ bias, int tid) {
  for (int u = tid; u < 2 * J; u += NTHR) {
    const int eb = (u >= J) ? 1 : 0;
    const int j  = u - eb * J;
    const int e0 = eb * 8;
    const float* mp = Mblk + (size_t)j * 4;
    float acc[8];
#pragma unroll
    for (int i = 0; i < 8; ++i) acc[i] = 0.f;
#pragma unroll 4
    for (int kb = 0; kb < KB; ++kb) {
      const float4 m = *(const float4*)(mp + (size_t)kb * J * 4);
#pragma unroll
      for (int i = 0; i < 8; ++i) {
        const float4 a = *(const float4*)(&in[e0 + i][kb * 4]);
        acc[i] += a.x * m.x + a.y * m.y + a.z * m.z + a.w * m.w;
      }
    }
    const float bj = bias[j];
#pragma unroll
    for (int i = 0; i < 8; ++i) outl[e0 + i][j] = acc[i] + bj;
  }
}

__device__ __forceinline__ void gru_gates(float (*h)[128], const float (*mx)[376],
                                          const float (*mi)[376], int tid) {
  for (int i = tid; i < EB * UNITS; i += NTHR) {
    int le = i / UNITS, u = i - le * UNITS;
    float xz = mx[le][u],           rz = mi[le][u];
    float xr = mx[le][UNITS + u],   rr = mi[le][UNITS + u];
    float xh = mx[le][2*UNITS + u], rh = mi[le][2*UNITS + u];
    float z  = 1.f / (1.f + expf(-(xz + rz)));
    float r  = 1.f / (1.f + expf(-(xr + rr)));
    float hh = tanhf(xh + r * rh);
    h[le][u] = z * h[le][u] + (1.f - z) * hh;
  }
}

// ---------- main persistent kernel: 256 WGs x 768 thr, 16 batch rows per WG ----------
__global__ __launch_bounds__(NTHR) void gru_main(
    const float* __restrict__ inputs, const float* __restrict__ b,
    const float* __restrict__ eps_s, const float* __restrict__ ws,
    float* __restrict__ out) {
  __shared__ float sh_h [EB][128];
  __shared__ float sh_x [EB][104];
  __shared__ float sh_mx[EB][376];
  __shared__ float sh_mi[EB][376];

  const int tid = threadIdx.x;
  const int e0g = blockIdx.x * EB;

  const float* Wblk = ws + WBLK_OFF;
  const float* Ublk = ws + UBLK_OFF;
  const float* Kblk = ws + KBLK_OFF;
  const float* Bias = ws + BIAS_OFF;
  const float* b0   = b;
  const float* b1   = b + THREE_U;

  for (int i = tid; i < EB * 128; i += NTHR) ((float*)sh_h)[i] = 0.f;
  __syncthreads();

  // ---- warmup: 56 GRU steps over inputs[:, t, :] ----
  for (int t = 0; t < TW; ++t) {
    gemv_tile<THREE_U, UKB, 128, 376>(sh_h, sh_mi, Ublk, b1, tid);   // mi = h@U + b1
    for (int i = tid; i < EB * 104; i += NTHR) {                      // stage x
      int le = i / 104, k = i - le * 104;
      float v = 0.f;
      if (k < NF) v = inputs[((size_t)(e0g + le) * T_IN + t) * NF + k];
      sh_x[le][k] = v;
    }
    __syncthreads();
    gemv_tile<THREE_U, WKB, 104, 376>(sh_x, sh_mx, Wblk, b0, tid);   // mx = x@Wk + b0
    __syncthreads();
    gru_gates(sh_h, sh_mx, sh_mi, tid);
    __syncthreads();
  }

  // ---- feedback: 28 dense outputs, 27 GRU steps in between ----
  for (int s = 0; s < GAMMA_; ++s) {
    // y = h @ kernel_s + bias_s  -> sh_mx[.][0..201]   (no barrier needed vs U gemv:
    // disjoint outputs, both read only sh_h)
    gemv_tile<OUT_DIM, UKB, 128, 376>(sh_h, sh_mx, Kblk + (size_t)s * (32 * OUT_DIM * 4),
                                      Bias + s * OUT_DIM, tid);
    if (s < GAMMA_ - 1)
      gemv_tile<THREE_U, UKB, 128, 376>(sh_h, sh_mi, Ublk, b1, tid); // mi = h@U + b1
    __syncthreads();

    // write output (loc / transformed scale)
    for (int i = tid; i < EB * OUT_DIM; i += NTHR) {
      int le = i / OUT_DIM, c = i - le * OUT_DIM;
      float v = sh_mx[le][c];
      float r = (c < NF) ? v : (1e-5f + 0.05f * softplusf_(CLOG + v));
      out[((size_t)(e0g + le) * GAMMA_ + s) * OUT_DIM + c] = r;
    }
    if (s < GAMMA_ - 1) {
      // x = loc + scale * eps_s[s]
      for (int i = tid; i < EB * 104; i += NTHR) {
        int le = i / 104, k = i - le * 104;
        float v = 0.f;
        if (k < NF) {
          float loc = sh_mx[le][k];
          float sc  = 1e-5f + 0.05f * softplusf_(CLOG + sh_mx[le][NF + k]);
          float es  = eps_s[((size_t)s * B_TOT + (e0g + le)) * NF + k];
          v = loc + sc * es;
        }
        sh_x[le][k] = v;
      }
      __syncthreads();
      gemv_tile<THREE_U, WKB, 104, 376>(sh_x, sh_mx, Wblk, b0, tid);
      __syncthreads();
      gru_gates(sh_h, sh_mx, sh_mi, tid);
      __syncthreads();
    }
  }
}

extern "C" void kernel_launch(void* const* d_in, const int* in_sizes, int n_in,
                              void* d_out, int out_size, void* d_ws, size_t ws_size,
                              hipStream_t stream) {
  const float* inputs = (const float*)d_in[0];
  const float* Wk     = (const float*)d_in[1];
  const float* U      = (const float*)d_in[2];
  const float* b      = (const float*)d_in[3];
  const float* dv_loc = (const float*)d_in[4];
  const float* dv_rho = (const float*)d_in[5];
  const float* eps_w0 = (const float*)d_in[6];
  const float* eps_w  = (const float*)d_in[7];
  const float* eps_s  = (const float*)d_in[8];
  float* out = (float*)d_out;
  float* ws  = (float*)d_ws;

  hipLaunchKernelGGL(setup_wu, dim3((87000 + 255) / 256), dim3(256), 0, stream, Wk, U, ws);
  hipLaunchKernelGGL(setup_kb, dim3((723968 + 28 * OUT_DIM + 255) / 256), dim3(256), 0, stream,
                     dv_loc, dv_rho, eps_w0, eps_w, ws);
  hipLaunchKernelGGL(gru_main, dim3(B_TOT / EB), dim3(NTHR), 0, stream,
                     inputs, b, eps_s, ws, out);
}

// Round 6
// 1601.676 us; speedup vs baseline: 1.4785x; 1.4785x over previous
//
#include <hip/hip_runtime.h>
#include <math.h>

typedef unsigned short ushort_t;
typedef __attribute__((ext_vector_type(8))) short short8;
typedef __attribute__((ext_vector_type(4))) float f32x4;

// ---- problem constants ----
constexpr int NF      = 101;
constexpr int UNITS   = 125;
constexpr int THREE_U = 375;
constexpr int OUT_DIM = 202;
constexpr int B_TOT   = 4096;
constexpr int T_IN    = 70;
constexpr int TW      = 56;
constexpr int GAMMA_  = 28;
constexpr int KS_     = UNITS * OUT_DIM;
constexpr int N_W     = KS_ + OUT_DIM;
constexpr float CLOG  = 0.54132485466f;
constexpr float L2E   = 1.44269504089f;
constexpr float LN2   = 0.69314718056f;

constexpr int NT_U = 24;   // 375 -> 384 cols (16-wide tiles)
constexpr int NT_K = 13;   // 202 -> 208
constexpr int NTHR = 512;
constexpr int EB   = 16;   // batch rows per WG

// ws layout: fp32 fragment-ordered weights (split to bf16x3 on the fly)
constexpr int NU_SET = 4 * NT_U * 512;   // 49152 floats (U or W)
constexpr int NK_SET = 4 * NT_K * 512;   // 26624 floats (per s)
constexpr int U_OFF  = 0;
constexpr int W_OFF  = NU_SET;                    // 49152
constexpr int K_OFF  = 2 * NU_SET;                // 98304
constexpr int KB_OFF = K_OFF + 28 * NK_SET;       // 843776
constexpr int TOT_ALL = KB_OFF + 28 * 208;        // 849600 floats = 3.40 MB

__device__ __forceinline__ float softplusf_(float x) {   // accurate (setup only)
  return (x > 0.f) ? (x + log1pf(expf(-x))) : log1pf(expf(x));
}
// fast device transcendentals
__device__ __forceinline__ float fexp2(float x) { return __builtin_amdgcn_exp2f(x); }
__device__ __forceinline__ float flog2(float x) { return __builtin_amdgcn_logf(x); }
__device__ __forceinline__ float frcp (float x) { return __builtin_amdgcn_rcpf(x); }
__device__ __forceinline__ float fsigm(float x) { return frcp(1.f + fexp2(-x * L2E)); }
__device__ __forceinline__ float ftanh(float x) { return 1.f - 2.f * frcp(1.f + fexp2(x * (2.f * L2E))); }
__device__ __forceinline__ float fsoftplus(float x) {
  float e = fexp2(-fabsf(x) * L2E);
  return fmaxf(x, 0.f) + LN2 * flog2(1.f + e);
}
__device__ __forceinline__ ushort_t f2bf(float v) {   // RNE float->bf16 bits
  unsigned int u = __float_as_uint(v);
  return (ushort_t)((u + 0x7fffu + ((u >> 16) & 1u)) >> 16);
}
__device__ __forceinline__ float bf2f(ushort_t b) {
  return __uint_as_float(((unsigned int)b) << 16);
}
// exact 3-way truncation split: v = b0 + b1 + b2 + O(2^-25 v)
__device__ __forceinline__ void split3(float v, ushort_t& o0, ushort_t& o1, ushort_t& o2) {
  unsigned int u  = __float_as_uint(v);
  unsigned int h0 = u & 0xffff0000u;
  float r  = v - __uint_as_float(h0);          // exact
  unsigned int u1 = __float_as_uint(r);
  unsigned int h1 = u1 & 0xffff0000u;
  float r2 = r - __uint_as_float(h1);          // exact
  o0 = (ushort_t)(h0 >> 16);
  o1 = (ushort_t)(h1 >> 16);
  o2 = f2bf(r2);
}
__device__ __forceinline__ f32x4 mfma16(short8 a, short8 b, f32x4 c) {
  return __builtin_amdgcn_mfma_f32_16x16x32_bf16(a, b, c, 0, 0, 0);
}

// ---------- setup: permute U, Wk, 28 variational kernels into fp32 B-frag order ----------
// frag layout per tile (kt,nt): lane l, elem i <-> M[k=kt*32+(l>>4)*8+i][n=nt*16+(l&15)]
// stored at ((kt*NT+nt)*64+l)*8+i
__global__ void setup_frags(const float* __restrict__ Wk, const float* __restrict__ U,
                            const float* __restrict__ dv_loc, const float* __restrict__ dv_rho,
                            const float* __restrict__ eps_w0, const float* __restrict__ eps_w,
                            float* __restrict__ wsf) {
  int idx = blockIdx.x * 256 + threadIdx.x;
  if (idx < NU_SET) {                                   // U (K=125)
    int i = idx & 7, l = (idx >> 3) & 63, q = idx >> 9;
    int nt = q % NT_U, kt = q / NT_U;
    int k = kt * 32 + ((l >> 4) << 3) + i, n = nt * 16 + (l & 15);
    wsf[U_OFF + idx] = (k < UNITS && n < THREE_U) ? U[k * THREE_U + n] : 0.f;
  } else if (idx < 2 * NU_SET) {                        // Wk (K=101)
    int r = idx - NU_SET;
    int i = r & 7, l = (r >> 3) & 63, q = r >> 9;
    int nt = q % NT_U, kt = q / NT_U;
    int k = kt * 32 + ((l >> 4) << 3) + i, n = nt * 16 + (l & 15);
    wsf[W_OFF + r] = (k < NF && n < THREE_U) ? Wk[k * THREE_U + n] : 0.f;
  } else if (idx < 2 * NU_SET + 28 * NK_SET) {          // 28 variational kernels
    int r = idx - 2 * NU_SET;
    int s = r / NK_SET, rr = r - s * NK_SET;
    int i = rr & 7, l = (rr >> 3) & 63, q = rr >> 9;
    int nt = q % NT_K, kt = q / NT_K;
    int k = kt * 32 + ((l >> 4) << 3) + i, o = nt * 16 + (l & 15);
    float v = 0.f;
    if (k < UNITS && o < OUT_DIM) {
      int n = k * OUT_DIM + o;
      const float* er = (s == 0) ? eps_w0 : (eps_w + (size_t)(s - 1) * N_W);
      float sig = 1e-5f + 0.01f * softplusf_(CLOG + dv_rho[n]);
      v = dv_loc[n] + sig * er[n];
    }
    wsf[K_OFF + r] = v;
  } else if (idx < TOT_ALL) {                           // K biases padded to 208
    int r = idx - (2 * NU_SET + 28 * NK_SET);
    int o = r % 208, s = r / 208;
    float v = 0.f;
    if (o < OUT_DIM) {
      int n = KS_ + o;
      const float* er = (s == 0) ? eps_w0 : (eps_w + (size_t)(s - 1) * N_W);
      float sig = 1e-5f + 0.01f * softplusf_(CLOG + dv_rho[n]);
      v = dv_loc[n] + sig * er[n];
    }
    wsf[KB_OFF + r] = v;
  }
}

// ---------- main persistent kernel: 256 WGs x 512 thr (8 waves), EB=16 rows ----------
__global__ __launch_bounds__(NTHR, 2) void gru_main(
    const float* __restrict__ inputs, const float* __restrict__ b,
    const float* __restrict__ eps_s, const float* __restrict__ wsf,
    float* __restrict__ out) {
  __shared__ float sh_h [EB][128];
  __shared__ float sh_mx[EB][388];
  __shared__ float sh_mi[EB][388];
  __shared__ __align__(16) ushort_t hfr[3][4][64][8];     // [set][kt][lane][el]
  __shared__ __align__(16) ushort_t xfr[2][3][4][64][8];  // [buf][set][kt][lane][el]

  const int tid = threadIdx.x, lane = tid & 63, wid = tid >> 6;
  const int e0g = blockIdx.x * EB;
  const float* b0 = b;
  const float* b1 = b + THREE_U;
  const float* kbias = wsf + KB_OFF;

  for (int i = tid; i < 3 * 4 * 64 * 8; i += NTHR) ((ushort_t*)hfr)[i] = 0;
  for (int i = tid; i < 2 * 3 * 4 * 64 * 8; i += NTHR) ((ushort_t*)xfr)[i] = 0;
  for (int i = tid; i < EB * 128; i += NTHR) ((float*)sh_h)[i] = 0.f;

  short8 ah[3][4], ax[3][4];

  auto load_ah = [&]() {
#pragma unroll
    for (int t2 = 0; t2 < 3; ++t2)
#pragma unroll
      for (int kt = 0; kt < 4; ++kt) ah[t2][kt] = *(const short8*)&hfr[t2][kt][lane][0];
  };
  auto load_ax = [&](int buf) {
#pragma unroll
    for (int t2 = 0; t2 < 3; ++t2)
#pragma unroll
      for (int kt = 0; kt < 4; ++kt) ax[t2][kt] = *(const short8*)&xfr[buf][t2][kt][lane][0];
  };
  auto loadsplit = [&](const float* base, short8& s0, short8& s1, short8& s2) {
    float4 p0 = *(const float4*)base;
    float4 p1 = *(const float4*)(base + 4);
    float vv[8] = {p0.x, p0.y, p0.z, p0.w, p1.x, p1.y, p1.z, p1.w};
#pragma unroll
    for (int i = 0; i < 8; ++i) {
      ushort_t a0, a1, a2;
      split3(vv[i], a0, a1, a2);
      s0[i] = (short)a0; s1[i] = (short)a1; s2[i] = (short)a2;
    }
  };
  // 8-term bf16x3 product accumulate (drops only a2*b2 ~ 2^-32)
  auto acc8 = [&](f32x4 c, const short8 (&A)[3][4], int kt, short8 w0, short8 w1, short8 w2) -> f32x4 {
    c = mfma16(A[0][kt], w0, c);
    c = mfma16(A[0][kt], w1, c);
    c = mfma16(A[1][kt], w0, c);
    c = mfma16(A[1][kt], w1, c);
    c = mfma16(A[0][kt], w2, c);
    c = mfma16(A[2][kt], w0, c);
    c = mfma16(A[1][kt], w2, c);
    c = mfma16(A[2][kt], w1, c);
    return c;
  };

  auto stage_x = [&](int t, int buf) {   // inputs[:, t, :] -> bf16x3 A-frags
    if (tid < 256) {
      int kt = tid >> 6, l = tid & 63;
      int row = l & 15, k0 = kt * 32 + ((l >> 4) << 3);
      const float* src = inputs + ((size_t)(e0g + row) * T_IN + t) * NF;
      short8 v0, v1, v2;
#pragma unroll
      for (int i2 = 0; i2 < 8; ++i2) {
        int k = k0 + i2;
        float v = (k < NF) ? src[k] : 0.f;
        ushort_t a0, a1, a2;
        split3(v, a0, a1, a2);
        v0[i2] = (short)a0; v1[i2] = (short)a1; v2[i2] = (short)a2;
      }
      *(short8*)&xfr[buf][0][kt][l][0] = v0;
      *(short8*)&xfr[buf][1][kt][l][0] = v1;
      *(short8*)&xfr[buf][2][kt][l][0] = v2;
    }
  };

  // 3 column-tiles per wave over 24: stream fp32 frags, split, 8-term MFMA
  auto gemm_uw = [&](const short8 (&A)[3][4], const float* Mf, const float* bias,
                     float (*dst)[388]) {
    f32x4 c0 = {0,0,0,0}, c1 = {0,0,0,0}, c2 = {0,0,0,0};
#pragma unroll
    for (int kt = 0; kt < 4; ++kt) {
      short8 w00, w01, w02, w10, w11, w12, w20, w21, w22;
      loadsplit(Mf + ((size_t)((kt * NT_U + wid     ) * 64 + lane)) * 8, w00, w01, w02);
      loadsplit(Mf + ((size_t)((kt * NT_U + wid + 8 ) * 64 + lane)) * 8, w10, w11, w12);
      loadsplit(Mf + ((size_t)((kt * NT_U + wid + 16) * 64 + lane)) * 8, w20, w21, w22);
      c0 = acc8(c0, A, kt, w00, w01, w02);
      c1 = acc8(c1, A, kt, w10, w11, w12);
      c2 = acc8(c2, A, kt, w20, w21, w22);
    }
    const int col = lane & 15, rg = (lane >> 4) << 2;
    const int cg0 = wid * 16 + col, cg1 = cg0 + 128, cg2 = cg0 + 256;
    float bv0 = bias[cg0], bv1 = bias[cg1];
    float bv2 = (cg2 < THREE_U) ? bias[cg2] : 0.f;
#pragma unroll
    for (int r = 0; r < 4; ++r) {
      dst[rg + r][cg0] = c0[r] + bv0;
      dst[rg + r][cg1] = c1[r] + bv1;
      dst[rg + r][cg2] = c2[r] + bv2;
    }
  };

  auto gemm_k = [&](int s) {   // y = h @ kernel_s + bias_s -> sh_mx[.][0..207]
    f32x4 c0 = {0,0,0,0}, c1 = {0,0,0,0};
    const float* Mf = wsf + K_OFF + (size_t)s * NK_SET;
    const bool two = (wid < 5);
#pragma unroll
    for (int kt = 0; kt < 4; ++kt) {
      short8 w00, w01, w02;
      loadsplit(Mf + ((size_t)((kt * NT_K + wid) * 64 + lane)) * 8, w00, w01, w02);
      c0 = acc8(c0, ah, kt, w00, w01, w02);
      if (two) {
        short8 w10, w11, w12;
        loadsplit(Mf + ((size_t)((kt * NT_K + wid + 8) * 64 + lane)) * 8, w10, w11, w12);
        c1 = acc8(c1, ah, kt, w10, w11, w12);
      }
    }
    const int col = lane & 15, rg = (lane >> 4) << 2;
    const int cg0 = wid * 16 + col;
    float bv0 = kbias[s * 208 + cg0];
#pragma unroll
    for (int r = 0; r < 4; ++r) sh_mx[rg + r][cg0] = c0[r] + bv0;
    if (two) {
      const int cg1 = cg0 + 128;
      float bv1 = kbias[s * 208 + cg1];
#pragma unroll
      for (int r = 0; r < 4; ++r) sh_mx[rg + r][cg1] = c1[r] + bv1;
    }
  };

  auto gates = [&]() {   // h = z*h + (1-z)*hh ; emit h A-fragments (bf16x3)
    for (int i = tid; i < EB * UNITS; i += NTHR) {
      int le = i / UNITS, u = i - le * UNITS;
      float xz = sh_mx[le][u],             rz = sh_mi[le][u];
      float xr = sh_mx[le][UNITS + u],     rr = sh_mi[le][UNITS + u];
      float xh = sh_mx[le][2 * UNITS + u], rh = sh_mi[le][2 * UNITS + u];
      float z  = fsigm(xz + rz);
      float r  = fsigm(xr + rr);
      float hh = ftanh(xh + r * rh);
      float hn = z * sh_h[le][u] + (1.f - z) * hh;
      sh_h[le][u] = hn;
      ushort_t a0, a1, a2;
      split3(hn, a0, a1, a2);
      int kt = u >> 5, ln = ((u >> 3) & 3) * 16 + le, el = u & 7;
      hfr[0][kt][ln][el] = a0;
      hfr[1][kt][ln][el] = a1;
      hfr[2][kt][ln][el] = a2;
    }
  };

  __syncthreads();          // zero-init visible
  stage_x(0, 0);
  __syncthreads();

  // ---- warmup: 56 GRU steps (2 barriers/step, x double-buffered) ----
  for (int t = 0; t < TW; ++t) {
    load_ah(); load_ax(t & 1);
    if (t + 1 < TW) stage_x(t + 1, (t + 1) & 1);
    gemm_uw(ax, wsf + W_OFF, b0, sh_mx);   // mx = x@Wk + b0
    gemm_uw(ah, wsf + U_OFF, b1, sh_mi);   // mi = h@U + b1
    __syncthreads();
    gates();
    __syncthreads();
  }

  // ---- feedback: 28 dense outputs, 27 GRU steps ----
  for (int s = 0; s < GAMMA_; ++s) {
    load_ah();
    gemm_k(s);                                          // y -> sh_mx[0..207]
    if (s < GAMMA_ - 1) gemm_uw(ah, wsf + U_OFF, b1, sh_mi);
    __syncthreads();

    for (int i = tid; i < EB * OUT_DIM; i += NTHR) {    // write output
      int le = i / OUT_DIM, c = i - le * OUT_DIM;
      float v = sh_mx[le][c];
      float rv = (c < NF) ? v : (1e-5f + 0.05f * fsoftplus(CLOG + v));
      out[((size_t)(e0g + le) * GAMMA_ + s) * OUT_DIM + c] = rv;
    }
    if (s < GAMMA_ - 1) {
      for (int i = tid; i < EB * NF; i += NTHR) {       // x = loc + scale*eps -> frags
        int le = i / NF, k = i - le * NF;
        float loc = sh_mx[le][k];
        float sc  = 1e-5f + 0.05f * fsoftplus(CLOG + sh_mx[le][NF + k]);
        float es  = eps_s[((size_t)s * B_TOT + (e0g + le)) * NF + k];
        float v = loc + sc * es;
        ushort_t a0, a1, a2;
        split3(v, a0, a1, a2);
        int kt = k >> 5, ln = ((k >> 3) & 3) * 16 + le, el = k & 7;
        xfr[0][0][kt][ln][el] = a0;
        xfr[0][1][kt][ln][el] = a1;
        xfr[0][2][kt][ln][el] = a2;
      }
      __syncthreads();
      load_ax(0);
      gemm_uw(ax, wsf + W_OFF, b0, sh_mx);   // mx = x@Wk + b0 (overwrites y)
      __syncthreads();
      gates();
      __syncthreads();
    }
  }
}

extern "C" void kernel_launch(void* const* d_in, const int* in_sizes, int n_in,
                              void* d_out, int out_size, void* d_ws, size_t ws_size,
                              hipStream_t stream) {
  const float* inputs = (const float*)d_in[0];
  const float* Wk     = (const float*)d_in[1];
  const float* U      = (const float*)d_in[2];
  const float* b      = (const float*)d_in[3];
  const float* dv_loc = (const float*)d_in[4];
  const float* dv_rho = (const float*)d_in[5];
  const float* eps_w0 = (const float*)d_in[6];
  const float* eps_w  = (const float*)d_in[7];
  const float* eps_s  = (const float*)d_in[8];
  float* out = (float*)d_out;
  float* wsf = (float*)d_ws;

  hipLaunchKernelGGL(setup_frags, dim3((TOT_ALL + 255) / 256), dim3(256), 0, stream,
                     Wk, U, dv_loc, dv_rho, eps_w0, eps_w, wsf);
  hipLaunchKernelGGL(gru_main, dim3(B_TOT / EB), dim3(NTHR), 0, stream,
                     inputs, b, eps_s, wsf, out);
}

// Round 9
// 1209.350 us; speedup vs baseline: 1.9582x; 1.3244x over previous
//
#include <hip/hip_runtime.h>
#include <math.h>

typedef unsigned short ushort_t;
typedef __attribute__((ext_vector_type(8))) short short8;
typedef __attribute__((ext_vector_type(4))) float f32x4;

// ---- problem constants ----
constexpr int NF      = 101;
constexpr int UNITS   = 125;
constexpr int THREE_U = 375;
constexpr int OUT_DIM = 202;
constexpr int B_TOT   = 4096;
constexpr int T_IN    = 70;
constexpr int TW      = 56;
constexpr int GAMMA_  = 28;
constexpr int KS_     = UNITS * OUT_DIM;
constexpr int N_W     = KS_ + OUT_DIM;
constexpr float CLOG  = 0.54132485466f;
constexpr float L2E   = 1.44269504089f;
constexpr float LN2   = 0.69314718056f;

constexpr int NT_U = 24;   // 375 -> 384 cols (16-wide tiles)
constexpr int NT_K = 13;   // 202 -> 208
constexpr int NTHR = 1024; // 16 waves: x-team 0-7, h-team 8-15 -> 4 waves/SIMD
constexpr int EB   = 16;   // batch rows per WG (MFMA M)

// ws layout: fp32 fragment-ordered weights (split to bf16x3 on the fly)
constexpr int NU_SET = 4 * NT_U * 512;   // 49152 floats (U or W)
constexpr int NK_SET = 4 * NT_K * 512;   // 26624 floats (per s)
constexpr int U_OFF  = 0;
constexpr int W_OFF  = NU_SET;                    // 49152
constexpr int K_OFF  = 2 * NU_SET;                // 98304
constexpr int KB_OFF = K_OFF + 28 * NK_SET;       // 843776
constexpr int TOT_ALL = KB_OFF + 28 * 208;        // 849600 floats = 3.40 MB

__device__ __forceinline__ float softplusf_(float x) {   // accurate (setup only)
  return (x > 0.f) ? (x + log1pf(expf(-x))) : log1pf(expf(x));
}
// fast device transcendentals
__device__ __forceinline__ float fexp2(float x) { return __builtin_amdgcn_exp2f(x); }
__device__ __forceinline__ float flog2(float x) { return __builtin_amdgcn_logf(x); }
__device__ __forceinline__ float frcp (float x) { return __builtin_amdgcn_rcpf(x); }
__device__ __forceinline__ float fsigm(float x) { return frcp(1.f + fexp2(-x * L2E)); }
__device__ __forceinline__ float ftanh(float x) { return 1.f - 2.f * frcp(1.f + fexp2(x * (2.f * L2E))); }
__device__ __forceinline__ float fsoftplus(float x) {
  float e = fexp2(-fabsf(x) * L2E);
  return fmaxf(x, 0.f) + LN2 * flog2(1.f + e);
}
__device__ __forceinline__ ushort_t f2bf(float v) {   // RNE float->bf16 bits
  unsigned int u = __float_as_uint(v);
  return (ushort_t)((u + 0x7fffu + ((u >> 16) & 1u)) >> 16);
}
__device__ __forceinline__ float bf2f(ushort_t b) {
  return __uint_as_float(((unsigned int)b) << 16);
}
// exact 3-way truncation split: v = b0 + b1 + b2 + O(2^-25 v)
__device__ __forceinline__ void split3(float v, ushort_t& o0, ushort_t& o1, ushort_t& o2) {
  unsigned int u  = __float_as_uint(v);
  unsigned int h0 = u & 0xffff0000u;
  float r  = v - __uint_as_float(h0);          // exact
  unsigned int u1 = __float_as_uint(r);
  unsigned int h1 = u1 & 0xffff0000u;
  float r2 = r - __uint_as_float(h1);          // exact
  o0 = (ushort_t)(h0 >> 16);
  o1 = (ushort_t)(h1 >> 16);
  o2 = f2bf(r2);
}
__device__ __forceinline__ f32x4 mfma16(short8 a, short8 b, f32x4 c) {
  return __builtin_amdgcn_mfma_f32_16x16x32_bf16(a, b, c, 0, 0, 0);
}

// ---------- setup: permute U, Wk, 28 variational kernels into fp32 B-frag order ----------
// frag layout per tile (kt,nt): lane l, elem i <-> M[k=kt*32+(l>>4)*8+i][n=nt*16+(l&15)]
// stored at ((kt*NT+nt)*64+l)*8+i
__global__ void setup_frags(const float* __restrict__ Wk, const float* __restrict__ U,
                            const float* __restrict__ dv_loc, const float* __restrict__ dv_rho,
                            const float* __restrict__ eps_w0, const float* __restrict__ eps_w,
                            float* __restrict__ wsf) {
  int idx = blockIdx.x * 256 + threadIdx.x;
  if (idx < NU_SET) {                                   // U (K=125)
    int i = idx & 7, l = (idx >> 3) & 63, q = idx >> 9;
    int nt = q % NT_U, kt = q / NT_U;
    int k = kt * 32 + ((l >> 4) << 3) + i, n = nt * 16 + (l & 15);
    wsf[U_OFF + idx] = (k < UNITS && n < THREE_U) ? U[k * THREE_U + n] : 0.f;
  } else if (idx < 2 * NU_SET) {                        // Wk (K=101)
    int r = idx - NU_SET;
    int i = r & 7, l = (r >> 3) & 63, q = r >> 9;
    int nt = q % NT_U, kt = q / NT_U;
    int k = kt * 32 + ((l >> 4) << 3) + i, n = nt * 16 + (l & 15);
    wsf[W_OFF + r] = (k < NF && n < THREE_U) ? Wk[k * THREE_U + n] : 0.f;
  } else if (idx < 2 * NU_SET + 28 * NK_SET) {          // 28 variational kernels
    int r = idx - 2 * NU_SET;
    int s = r / NK_SET, rr = r - s * NK_SET;
    int i = rr & 7, l = (rr >> 3) & 63, q = rr >> 9;
    int nt = q % NT_K, kt = q / NT_K;
    int k = kt * 32 + ((l >> 4) << 3) + i, o = nt * 16 + (l & 15);
    float v = 0.f;
    if (k < UNITS && o < OUT_DIM) {
      int n = k * OUT_DIM + o;
      const float* er = (s == 0) ? eps_w0 : (eps_w + (size_t)(s - 1) * N_W);
      float sig = 1e-5f + 0.01f * softplusf_(CLOG + dv_rho[n]);
      v = dv_loc[n] + sig * er[n];
    }
    wsf[K_OFF + r] = v;
  } else if (idx < TOT_ALL) {                           // K biases padded to 208
    int r = idx - (2 * NU_SET + 28 * NK_SET);
    int o = r % 208, s = r / 208;
    float v = 0.f;
    if (o < OUT_DIM) {
      int n = KS_ + o;
      const float* er = (s == 0) ? eps_w0 : (eps_w + (size_t)(s - 1) * N_W);
      float sig = 1e-5f + 0.01f * softplusf_(CLOG + dv_rho[n]);
      v = dv_loc[n] + sig * er[n];
    }
    wsf[KB_OFF + r] = v;
  }
}

// ---------- main persistent kernel: 256 WGs x 1024 thr (16 waves), EB=16 rows ----------
__global__ __launch_bounds__(NTHR) void gru_main(
    const float* __restrict__ inputs, const float* __restrict__ b,
    const float* __restrict__ eps_s, const float* __restrict__ wsf,
    float* __restrict__ out) {
  __shared__ float sh_h [EB][128];
  __shared__ float sh_mx[EB][388];
  __shared__ float sh_mi[EB][388];
  __shared__ __align__(16) ushort_t hfr[3][4][64][8];     // [set][kt][lane][el] (single buf)
  __shared__ __align__(16) ushort_t xfr[2][3][4][64][8];  // [buf][set][kt][lane][el]

  const int tid = threadIdx.x, lane = tid & 63, wid = tid >> 6;   // wid 0..15
  const int e0g = blockIdx.x * EB;
  const float* b0 = b;
  const float* b1 = b + THREE_U;
  const float* kbias = wsf + KB_OFF;

  for (int i = tid; i < 3 * 4 * 64 * 8; i += NTHR) ((ushort_t*)hfr)[i] = 0;
  for (int i = tid; i < 2 * 3 * 4 * 64 * 8; i += NTHR) ((ushort_t*)xfr)[i] = 0;
  for (int i = tid; i < EB * 128; i += NTHR) ((float*)sh_h)[i] = 0.f;

  short8 ah[3][4], ax[3][4];

  auto load_ah = [&]() {
#pragma unroll
    for (int t2 = 0; t2 < 3; ++t2)
#pragma unroll
      for (int kt = 0; kt < 4; ++kt) ah[t2][kt] = *(const short8*)&hfr[t2][kt][lane][0];
  };
  auto load_ax = [&](int buf) {
#pragma unroll
    for (int t2 = 0; t2 < 3; ++t2)
#pragma unroll
      for (int kt = 0; kt < 4; ++kt) ax[t2][kt] = *(const short8*)&xfr[buf][t2][kt][lane][0];
  };
  auto loadsplit = [&](const float* base, short8& s0, short8& s1, short8& s2) {
    float4 p0 = *(const float4*)base;
    float4 p1 = *(const float4*)(base + 4);
    float vv[8] = {p0.x, p0.y, p0.z, p0.w, p1.x, p1.y, p1.z, p1.w};
#pragma unroll
    for (int i = 0; i < 8; ++i) {
      ushort_t a0, a1, a2;
      split3(vv[i], a0, a1, a2);
      s0[i] = (short)a0; s1[i] = (short)a1; s2[i] = (short)a2;
    }
  };
  // 8-term bf16x3 product accumulate (drops only a2*b2 ~ 2^-32)
  auto acc8 = [&](f32x4 c, const short8 (&A)[3][4], int kt, short8 w0, short8 w1, short8 w2) -> f32x4 {
    c = mfma16(A[0][kt], w0, c);
    c = mfma16(A[0][kt], w1, c);
    c = mfma16(A[1][kt], w0, c);
    c = mfma16(A[1][kt], w1, c);
    c = mfma16(A[0][kt], w2, c);
    c = mfma16(A[2][kt], w0, c);
    c = mfma16(A[1][kt], w2, c);
    c = mfma16(A[2][kt], w1, c);
    return c;
  };

  auto stage_x = [&](int t, int buf) {   // inputs[:, t, :] -> bf16x3 A-frags (waves 12-15)
    if (tid >= 768) {
      int q = tid - 768;
      int kt = q >> 6, l = q & 63;
      int row = l & 15, k0 = kt * 32 + ((l >> 4) << 3);
      const float* src = inputs + ((size_t)(e0g + row) * T_IN + t) * NF;
      short8 v0, v1, v2;
#pragma unroll
      for (int i2 = 0; i2 < 8; ++i2) {
        int k = k0 + i2;
        float v = (k < NF) ? src[k] : 0.f;
        ushort_t a0, a1, a2;
        split3(v, a0, a1, a2);
        v0[i2] = (short)a0; v1[i2] = (short)a1; v2[i2] = (short)a2;
      }
      *(short8*)&xfr[buf][0][kt][l][0] = v0;
      *(short8*)&xfr[buf][1][kt][l][0] = v1;
      *(short8*)&xfr[buf][2][kt][l][0] = v2;
    }
  };

  // 3-nt trio gemm: nt = base, base+8, base+16 (base in 0..7)
  auto gemm_trio = [&](const short8 (&A)[3][4], const float* Mf, const float* bias,
                       float (*dst)[388], int base) {
    f32x4 c0 = {0,0,0,0}, c1 = {0,0,0,0}, c2 = {0,0,0,0};
#pragma unroll
    for (int kt = 0; kt < 4; ++kt) {
      short8 w00, w01, w02, w10, w11, w12, w20, w21, w22;
      loadsplit(Mf + ((size_t)((kt * NT_U + base     ) * 64 + lane)) * 8, w00, w01, w02);
      loadsplit(Mf + ((size_t)((kt * NT_U + base + 8 ) * 64 + lane)) * 8, w10, w11, w12);
      loadsplit(Mf + ((size_t)((kt * NT_U + base + 16) * 64 + lane)) * 8, w20, w21, w22);
      c0 = acc8(c0, A, kt, w00, w01, w02);
      c1 = acc8(c1, A, kt, w10, w11, w12);
      c2 = acc8(c2, A, kt, w20, w21, w22);
    }
    const int col = lane & 15, rg = (lane >> 4) << 2;
    const int cg0 = base * 16 + col, cg1 = cg0 + 128, cg2 = cg0 + 256;
    float bv0 = bias[cg0], bv1 = bias[cg1];
    float bv2 = (cg2 < THREE_U) ? bias[cg2] : 0.f;
#pragma unroll
    for (int r = 0; r < 4; ++r) {
      dst[rg + r][cg0] = c0[r] + bv0;
      dst[rg + r][cg1] = c1[r] + bv1;
      dst[rg + r][cg2] = c2[r] + bv2;
    }
  };

  // feedback W-gemm: all 16 waves; nt = wid, plus wid+16 for wid<8
  auto gemm_wfb = [&]() {
    f32x4 c0 = {0,0,0,0}, c1 = {0,0,0,0};
    const float* Mf = wsf + W_OFF;
    const bool two = (wid < 8);
#pragma unroll
    for (int kt = 0; kt < 4; ++kt) {
      short8 w00, w01, w02;
      loadsplit(Mf + ((size_t)((kt * NT_U + wid) * 64 + lane)) * 8, w00, w01, w02);
      c0 = acc8(c0, ax, kt, w00, w01, w02);
      if (two) {
        short8 w10, w11, w12;
        loadsplit(Mf + ((size_t)((kt * NT_U + wid + 16) * 64 + lane)) * 8, w10, w11, w12);
        c1 = acc8(c1, ax, kt, w10, w11, w12);
      }
    }
    const int col = lane & 15, rg = (lane >> 4) << 2;
    const int cg0 = wid * 16 + col;
    float bv0 = (cg0 < THREE_U) ? b0[cg0] : 0.f;
#pragma unroll
    for (int r = 0; r < 4; ++r) sh_mx[rg + r][cg0] = c0[r] + bv0;
    if (two) {
      const int cg1 = (wid + 16) * 16 + col;
      float bv1 = (cg1 < THREE_U) ? b0[cg1] : 0.f;
#pragma unroll
      for (int r = 0; r < 4; ++r) sh_mx[rg + r][cg1] = c1[r] + bv1;
    }
  };

  // feedback K-gemm: waves 8-15; nt = wid-8, plus wid-8+8 for wid-8<5
  auto gemm_kfb = [&](int s) {
    f32x4 c0 = {0,0,0,0}, c1 = {0,0,0,0};
    const float* Mf = wsf + K_OFF + (size_t)s * NK_SET;
    const int kw = wid - 8;
    const bool two = (kw < 5);
#pragma unroll
    for (int kt = 0; kt < 4; ++kt) {
      short8 w00, w01, w02;
      loadsplit(Mf + ((size_t)((kt * NT_K + kw) * 64 + lane)) * 8, w00, w01, w02);
      c0 = acc8(c0, ah, kt, w00, w01, w02);
      if (two) {
        short8 w10, w11, w12;
        loadsplit(Mf + ((size_t)((kt * NT_K + kw + 8) * 64 + lane)) * 8, w10, w11, w12);
        c1 = acc8(c1, ah, kt, w10, w11, w12);
      }
    }
    const int col = lane & 15, rg = (lane >> 4) << 2;
    const int cg0 = kw * 16 + col;
    float bv0 = kbias[s * 208 + cg0];
#pragma unroll
    for (int r = 0; r < 4; ++r) sh_mx[rg + r][cg0] = c0[r] + bv0;
    if (two) {
      const int cg1 = cg0 + 128;
      float bv1 = kbias[s * 208 + cg1];
#pragma unroll
      for (int r = 0; r < 4; ++r) sh_mx[rg + r][cg1] = c1[r] + bv1;
    }
  };

  auto gates = [&]() {   // h = z*h + (1-z)*hh ; emit h A-fragments (bf16x3)
    for (int i = tid; i < EB * UNITS; i += NTHR) {
      int le = i / UNITS, u = i - le * UNITS;
      float xz = sh_mx[le][u],             rz = sh_mi[le][u];
      float xr = sh_mx[le][UNITS + u],     rr = sh_mi[le][UNITS + u];
      float xh = sh_mx[le][2 * UNITS + u], rh = sh_mi[le][2 * UNITS + u];
      float z  = fsigm(xz + rz);
      float r  = fsigm(xr + rr);
      float hh = ftanh(xh + r * rh);
      float hn = z * sh_h[le][u] + (1.f - z) * hh;
      sh_h[le][u] = hn;
      ushort_t a0, a1, a2;
      split3(hn, a0, a1, a2);
      int kt = u >> 5, ln = ((u >> 3) & 3) * 16 + le, el = u & 7;
      hfr[0][kt][ln][el] = a0;
      hfr[1][kt][ln][el] = a1;
      hfr[2][kt][ln][el] = a2;
    }
  };

  __syncthreads();          // zero-init visible
  stage_x(0, 0);
  __syncthreads();

  // ---- warmup: 56 GRU steps, team-split gemms, 2 barriers/step ----
  for (int t = 0; t < TW; ++t) {
    if (wid < 8) {                       // x-team
      load_ax(t & 1);
      gemm_trio(ax, wsf + W_OFF, b0, sh_mx, wid);     // mx = x@Wk + b0
    } else {                             // h-team
      load_ah();
      if (t + 1 < TW) stage_x(t + 1, (t + 1) & 1);    // waves 12-15
      gemm_trio(ah, wsf + U_OFF, b1, sh_mi, wid - 8); // mi = h@U + b1
    }
    __syncthreads();
    gates();
    __syncthreads();
  }

  // ---- feedback: 28 dense outputs, 27 GRU steps ----
  for (int s = 0; s < GAMMA_; ++s) {
    load_ah();
    if (wid >= 8) gemm_kfb(s);                          // y -> sh_mx[0..207]
    else          gemm_trio(ah, wsf + U_OFF, b1, sh_mi, wid);  // mi = h@U + b1
    __syncthreads();

    for (int i = tid; i < EB * OUT_DIM; i += NTHR) {    // write output
      int le = i / OUT_DIM, c = i - le * OUT_DIM;
      float v = sh_mx[le][c];
      float rv = (c < NF) ? v : (1e-5f + 0.05f * fsoftplus(CLOG + v));
      out[((size_t)(e0g + le) * GAMMA_ + s) * OUT_DIM + c] = rv;
    }
    if (s < GAMMA_ - 1) {
      for (int i = tid; i < EB * NF; i += NTHR) {       // x = loc + scale*eps -> frags
        int le = i / NF, k = i - le * NF;
        float loc = sh_mx[le][k];
        float sc  = 1e-5f + 0.05f * fsoftplus(CLOG + sh_mx[le][NF + k]);
        float es  = eps_s[((size_t)s * B_TOT + (e0g + le)) * NF + k];
        float v = loc + sc * es;
        ushort_t a0, a1, a2;
        split3(v, a0, a1, a2);
        int kt = k >> 5, ln = ((k >> 3) & 3) * 16 + le, el = k & 7;
        xfr[0][0][kt][ln][el] = a0;
        xfr[0][1][kt][ln][el] = a1;
        xfr[0][2][kt][ln][el] = a2;
      }
      __syncthreads();
      load_ax(0);
      gemm_wfb();                                       // mx = x@Wk + b0 (overwrites y)
      __syncthreads();
      gates();
      __syncthreads();
    }
  }
}

extern "C" void kernel_launch(void* const* d_in, const int* in_sizes, int n_in,
                              void* d_out, int out_size, void* d_ws, size_t ws_size,
                              hipStream_t stream) {
  const float* inputs = (const float*)d_in[0];
  const float* Wk     = (const float*)d_in[1];
  const float* U      = (const float*)d_in[2];
  const float* b      = (const float*)d_in[3];
  const float* dv_loc = (const float*)d_in[4];
  const float* dv_rho = (const float*)d_in[5];
  const float* eps_w0 = (const float*)d_in[6];
  const float* eps_w  = (const float*)d_in[7];
  const float* eps_s  = (const float*)d_in[8];
  float* out = (float*)d_out;
  float* wsf = (float*)d_ws;

  hipLaunchKernelGGL(setup_frags, dim3((TOT_ALL + 255) / 256), dim3(256), 0, stream,
                     Wk, U, dv_loc, dv_rho, eps_w0, eps_w, wsf);
  hipLaunchKernelGGL(gru_main, dim3(B_TOT / EB), dim3(NTHR), 0, stream,
                     inputs, b, eps_s, wsf, out);
}